// Round 2
// baseline (92.406 us; speedup 1.0000x reference)
//
#include <hip/hip_runtime.h>

// OnlineTripletLoss: emb (8192,512) f32, triplets (131072,3) delivered as int32.
// out[0]=mean(exp((an-ap)/0.7)), out[1]=mean(1-ap), out[2]=mean(1-an),
// with ap,an clipped to [-1,1].

#define MARGIN_INV (1.0f / 0.7f)
#define D 512

constexpr int BLOCKS  = 2048;
constexpr int THREADS = 256;                 // 4 waves/block
constexpr int WAVES_PER_BLOCK = THREADS / 64;
constexpr int TOTAL_WAVES = BLOCKS * WAVES_PER_BLOCK;

__global__ __launch_bounds__(THREADS) void triplet_main(
    const float* __restrict__ emb,
    const int* __restrict__ trip,      // int32 per harness contract
    int T,
    float* __restrict__ partials /* [BLOCKS*3] */) {

    const int lane  = threadIdx.x & 63;
    const int wave  = threadIdx.x >> 6;
    const int gwave = blockIdx.x * WAVES_PER_BLOCK + wave;

    float s_loss = 0.f, s_ap = 0.f, s_an = 0.f;

    for (int t = gwave; t < T; t += TOTAL_WAVES) {
        const int i0 = trip[3 * t + 0];
        const int i1 = trip[3 * t + 1];
        const int i2 = trip[3 * t + 2];

        // lane l covers elements [8l, 8l+8): two float4 loads per row
        const float4* a4 = (const float4*)(emb + (size_t)i0 * D) + (lane << 1);
        const float4* p4 = (const float4*)(emb + (size_t)i1 * D) + (lane << 1);
        const float4* n4 = (const float4*)(emb + (size_t)i2 * D) + (lane << 1);

        const float4 a0 = a4[0], a1 = a4[1];
        const float4 p0 = p4[0], p1 = p4[1];
        const float4 n0 = n4[0], n1 = n4[1];

        float ap = a0.x * p0.x + a0.y * p0.y + a0.z * p0.z + a0.w * p0.w
                 + a1.x * p1.x + a1.y * p1.y + a1.z * p1.z + a1.w * p1.w;
        float an = a0.x * n0.x + a0.y * n0.y + a0.z * n0.z + a0.w * n0.w
                 + a1.x * n1.x + a1.y * n1.y + a1.z * n1.z + a1.w * n1.w;

        // 64-lane butterfly reduce (all lanes end with full sum)
        #pragma unroll
        for (int off = 32; off; off >>= 1) {
            ap += __shfl_xor(ap, off);
            an += __shfl_xor(an, off);
        }

        ap = fminf(fmaxf(ap, -1.0f), 1.0f);
        an = fminf(fmaxf(an, -1.0f), 1.0f);

        s_loss += __expf((an - ap) * MARGIN_INV);
        s_ap   += 1.0f - ap;
        s_an   += 1.0f - an;
    }

    __shared__ float red[WAVES_PER_BLOCK][3];
    if (lane == 0) {
        red[wave][0] = s_loss;
        red[wave][1] = s_ap;
        red[wave][2] = s_an;
    }
    __syncthreads();
    if (threadIdx.x == 0) {
        float a = 0.f, b = 0.f, c = 0.f;
        #pragma unroll
        for (int w = 0; w < WAVES_PER_BLOCK; ++w) {
            a += red[w][0]; b += red[w][1]; c += red[w][2];
        }
        partials[blockIdx.x * 3 + 0] = a;
        partials[blockIdx.x * 3 + 1] = b;
        partials[blockIdx.x * 3 + 2] = c;
    }
}

__global__ __launch_bounds__(256) void triplet_reduce(
    const float* __restrict__ partials, int nblocks, int T,
    float* __restrict__ out) {

    const int tid = threadIdx.x;
    float a = 0.f, b = 0.f, c = 0.f;
    for (int i = tid; i < nblocks; i += 256) {
        a += partials[3 * i + 0];
        b += partials[3 * i + 1];
        c += partials[3 * i + 2];
    }
    #pragma unroll
    for (int off = 32; off; off >>= 1) {
        a += __shfl_xor(a, off);
        b += __shfl_xor(b, off);
        c += __shfl_xor(c, off);
    }
    __shared__ float red[4][3];
    const int lane = tid & 63, wave = tid >> 6;
    if (lane == 0) { red[wave][0] = a; red[wave][1] = b; red[wave][2] = c; }
    __syncthreads();
    if (tid == 0) {
        float A = 0.f, B = 0.f, C = 0.f;
        #pragma unroll
        for (int w = 0; w < 4; ++w) { A += red[w][0]; B += red[w][1]; C += red[w][2]; }
        const float inv = 1.0f / (float)T;
        out[0] = A * inv;
        out[1] = B * inv;
        out[2] = C * inv;
    }
}

extern "C" void kernel_launch(void* const* d_in, const int* in_sizes, int n_in,
                              void* d_out, int out_size, void* d_ws, size_t ws_size,
                              hipStream_t stream) {
    const float* emb  = (const float*)d_in[0];
    const int*   trip = (const int*)d_in[1];
    float* out = (float*)d_out;
    float* partials = (float*)d_ws;   // BLOCKS*3 floats = 24 KB, well under ws_size

    const int T = in_sizes[1] / 3;    // 131072

    triplet_main<<<BLOCKS, THREADS, 0, stream>>>(emb, trip, T, partials);
    triplet_reduce<<<1, 256, 0, stream>>>(partials, BLOCKS, T, out);
}